// Round 2
// baseline (3029.514 us; speedup 1.0000x reference)
//
#include <hip/hip_runtime.h>
#include <hip/hip_bf16.h>
#include <math.h>

// DAGNN propagation:
//   deg[n]  = in-degree (incl. self loop), norm = deg^-0.5
//   h_0 = feats;  h_{k+1} = norm * segsum_{dst}( (norm*h_k)[src] )
//   out = sum_k sigmoid(h_k . s) * h_k      (streamed per hop, H never stored)

#define DIM 64

// ---- zero a float region (grid-stride) ----
__global__ void zero_kernel(float* __restrict__ p, long long n) {
    long long i = (long long)blockIdx.x * blockDim.x + threadIdx.x;
    long long stride = (long long)gridDim.x * blockDim.x;
    for (; i < n; i += stride) p[i] = 0.0f;
}

// ---- in-degree via atomics ----
__global__ void degree_kernel(const int* __restrict__ dst, float* __restrict__ deg, int E) {
    int e = blockIdx.x * blockDim.x + threadIdx.x;
    if (e < E) atomicAdd(&deg[dst[e]], 1.0f);
}

// ---- norm = deg^-0.5 (in place) ----
__global__ void norm_kernel(float* __restrict__ deg, int N) {
    int i = blockIdx.x * blockDim.x + threadIdx.x;
    if (i < N) deg[i] = rsqrtf(deg[i]);
}

// ---- out = sigmoid(feats . s) * feats   (k=0 term, plain write) ----
__global__ void init_out_kernel(const float* __restrict__ feats,
                                const float* __restrict__ s,
                                float* __restrict__ out, int N) {
    int n = blockIdx.x * (blockDim.x >> 6) + (threadIdx.x >> 6);
    int lane = threadIdx.x & 63;
    if (n >= N) return;
    float v = feats[(size_t)n * DIM + lane];
    float p = v * s[lane];
    #pragma unroll
    for (int off = 32; off; off >>= 1) p += __shfl_xor(p, off, 64);
    float gate = 1.0f / (1.0f + __expf(-p));
    out[(size_t)n * DIM + lane] = gate * v;
}

// ---- edge scatter: nxt[dst,:] += h[src,:] * norm[src]; one wave per edge ----
__global__ void scatter_kernel(const float* __restrict__ h,
                               const float* __restrict__ norm,
                               const int* __restrict__ src,
                               const int* __restrict__ dst,
                               float* __restrict__ nxt, int E) {
    int e = blockIdx.x * (blockDim.x >> 6) + (threadIdx.x >> 6);
    int lane = threadIdx.x & 63;
    if (e >= E) return;
    int sI = src[e];
    int dI = dst[e];
    float v = h[(size_t)sI * DIM + lane] * norm[sI];
    atomicAdd(&nxt[(size_t)dI * DIM + lane], v);
}

// ---- per-node epilogue: post-scale, gate, accumulate out, zero other buffer ----
__global__ void epilogue_kernel(float* __restrict__ cur,     // raw sums in, scaled h out
                                float* __restrict__ other,   // zeroed for next hop's scatter
                                const float* __restrict__ norm,
                                const float* __restrict__ s,
                                float* __restrict__ out,
                                int N, int zero_other) {
    int n = blockIdx.x * (blockDim.x >> 6) + (threadIdx.x >> 6);
    int lane = threadIdx.x & 63;
    if (n >= N) return;
    size_t idx = (size_t)n * DIM + lane;
    float v = cur[idx] * norm[n];
    cur[idx] = v;
    float p = v * s[lane];
    #pragma unroll
    for (int off = 32; off; off >>= 1) p += __shfl_xor(p, off, 64);
    float gate = 1.0f / (1.0f + __expf(-p));
    out[idx] += gate * v;
    if (zero_other) other[idx] = 0.0f;
}

extern "C" void kernel_launch(void* const* d_in, const int* in_sizes, int n_in,
                              void* d_out, int out_size, void* d_ws, size_t ws_size,
                              hipStream_t stream) {
    const float* feats = (const float*)d_in[0];
    const float* s     = (const float*)d_in[1];
    const int*   src   = (const int*)d_in[2];
    const int*   dst   = (const int*)d_in[3];
    float* out = (float*)d_out;

    const int N = in_sizes[0] / DIM;
    const int E = in_sizes[2];

    // workspace layout: [norm: N][bufA: N*DIM][bufB: N*DIM]  (~51.6 MB)
    float* norm = (float*)d_ws;
    float* bufA = norm + N;
    float* bufB = bufA + (size_t)N * DIM;

    const int BLK = 256;
    const int wavesPerBlk = BLK / 64;

    // zero norm + bufA (contiguous region)
    {
        long long zn = (long long)N + (long long)N * DIM;
        zero_kernel<<<2048, BLK, 0, stream>>>(norm, zn);
    }
    // degrees -> norm
    degree_kernel<<<(E + BLK - 1) / BLK, BLK, 0, stream>>>(dst, norm, E);
    norm_kernel<<<(N + BLK - 1) / BLK, BLK, 0, stream>>>(norm, N);

    // k = 0 readout term
    init_out_kernel<<<(N + wavesPerBlk - 1) / wavesPerBlk, BLK, 0, stream>>>(feats, s, out, N);

    const int K = 10;
    const float* hsrc = feats;    // scatter source for hop 0
    float* target = bufA;         // zeroed
    float* other  = bufB;         // zeroed by hop-0 epilogue

    int scatterBlocks = (E + wavesPerBlk - 1) / wavesPerBlk;
    int nodeBlocks    = (N + wavesPerBlk - 1) / wavesPerBlk;

    for (int k = 0; k < K; ++k) {
        scatter_kernel<<<scatterBlocks, BLK, 0, stream>>>(hsrc, norm, src, dst, target, E);
        int zero_other = (k < K - 1) ? 1 : 0;
        epilogue_kernel<<<nodeBlocks, BLK, 0, stream>>>(target, other, norm, s, out, N, zero_other);
        // ping-pong: target now holds h_{k+1} (scaled); other is zeroed
        hsrc = target;
        float* t = target; target = other; other = t;
    }
}

// Round 3
// 907.507 us; speedup vs baseline: 3.3383x; 3.3383x over previous
//
#include <hip/hip_runtime.h>
#include <hip/hip_bf16.h>
#include <math.h>

// DAGNN propagation, CSR-gather formulation (no float atomics in the hop loop):
//   deg[n]  = in-degree (incl. self loop), norm = deg^-0.5
//   w_0 = feats * norm                      (pre-scaled state)
//   per hop: acc[n] = sum_{j in CSR row n} w[col[j]]      (plain gather)
//            v = acc * norm[n]              (= h_{k+1}[n])
//            out[n] += sigmoid(v . s) * v   (streamed readout)
//            w_next[n] = v * norm[n]        (pre-scale for next hop)

#define DIM 64

// ---- zero int region ----
__global__ void zero_int_kernel(int* __restrict__ p, int n) {
    int i = blockIdx.x * blockDim.x + threadIdx.x;
    if (i < n) p[i] = 0;
}

// ---- in-degree (int atomics) ----
__global__ void degree_kernel(const int* __restrict__ dst, int* __restrict__ deg, int E) {
    int e = blockIdx.x * blockDim.x + threadIdx.x;
    if (e < E) atomicAdd(&deg[dst[e]], 1);
}

// ---- norm = deg^-0.5 ----
__global__ void norm_kernel(const int* __restrict__ deg, float* __restrict__ norm, int N) {
    int i = blockIdx.x * blockDim.x + threadIdx.x;
    if (i < N) norm[i] = rsqrtf((float)deg[i]);
}

// ---- exclusive scan, stage 1: per-1024-chunk scan + chunk totals ----
__global__ void scan1_kernel(const int* __restrict__ deg, int* __restrict__ rp,
                             int* __restrict__ chunk_sums, int N) {
    __shared__ int lds[256];
    int t = threadIdx.x;
    int base = blockIdx.x * 1024 + t * 4;
    int v0 = (base + 0 < N) ? deg[base + 0] : 0;
    int v1 = (base + 1 < N) ? deg[base + 1] : 0;
    int v2 = (base + 2 < N) ? deg[base + 2] : 0;
    int v3 = (base + 3 < N) ? deg[base + 3] : 0;
    int tsum = v0 + v1 + v2 + v3;
    lds[t] = tsum;
    __syncthreads();
    for (int off = 1; off < 256; off <<= 1) {
        int x = (t >= off) ? lds[t - off] : 0;
        __syncthreads();
        lds[t] += x;
        __syncthreads();
    }
    int excl = lds[t] - tsum;
    if (t == 255) chunk_sums[blockIdx.x] = lds[255];
    int p = excl;
    if (base + 0 < N) rp[base + 0] = p; p += v0;
    if (base + 1 < N) rp[base + 1] = p; p += v1;
    if (base + 2 < N) rp[base + 2] = p; p += v2;
    if (base + 3 < N) rp[base + 3] = p;
}

// ---- exclusive scan, stage 2: scan chunk totals (single block, B <= 256) ----
__global__ void scan2_kernel(int* __restrict__ chunk_sums, int B) {
    __shared__ int lds[256];
    int t = threadIdx.x;
    int v = (t < B) ? chunk_sums[t] : 0;
    lds[t] = v;
    __syncthreads();
    for (int off = 1; off < 256; off <<= 1) {
        int x = (t >= off) ? lds[t - off] : 0;
        __syncthreads();
        lds[t] += x;
        __syncthreads();
    }
    if (t < B) chunk_sums[t] = lds[t] - v;  // exclusive
}

// ---- exclusive scan, stage 3: add chunk offsets; init cursor; rp[N]=E ----
__global__ void scan3_kernel(int* __restrict__ rp, const int* __restrict__ chunk_sums,
                             int* __restrict__ cursor, int N, int E) {
    int i = blockIdx.x * blockDim.x + threadIdx.x;
    if (i < N) {
        int val = rp[i] + chunk_sums[i >> 10];
        rp[i] = val;
        cursor[i] = val;
    }
    if (i == 0) rp[N] = E;
}

// ---- CSR fill: col[pos] = src[e], pos allocated per dst row ----
__global__ void fill_kernel(const int* __restrict__ src, const int* __restrict__ dst,
                            int* __restrict__ cursor, int* __restrict__ col, int E) {
    int e = blockIdx.x * blockDim.x + threadIdx.x;
    if (e < E) {
        int d = dst[e];
        int pos = atomicAdd(&cursor[d], 1);
        col[pos] = src[e];
    }
}

// ---- init: out = sigmoid(feats.s)*feats ; w0 = feats*norm ----
__global__ void init_kernel(const float* __restrict__ feats,
                            const float* __restrict__ norm,
                            const float* __restrict__ s,
                            float* __restrict__ out,
                            float* __restrict__ w, int N) {
    int n = blockIdx.x * (blockDim.x >> 6) + (threadIdx.x >> 6);
    int lane = threadIdx.x & 63;
    if (n >= N) return;
    size_t idx = (size_t)n * DIM + lane;
    float v = feats[idx];
    float p = v * s[lane];
    #pragma unroll
    for (int off = 32; off; off >>= 1) p += __shfl_xor(p, off, 64);
    float gate = 1.0f / (1.0f + expf(-p));
    out[idx] = gate * v;
    w[idx] = v * norm[n];
}

// ---- fused hop: CSR gather + norm + gate + out-accum + next-state write ----
__global__ void gather_hop_kernel(const float* __restrict__ w,
                                  const int* __restrict__ rp,
                                  const int* __restrict__ col,
                                  const float* __restrict__ norm,
                                  const float* __restrict__ s,
                                  float* __restrict__ out,
                                  float* __restrict__ wnext,
                                  int N, int write_next) {
    int n = blockIdx.x * (blockDim.x >> 6) + (threadIdx.x >> 6);
    int lane = threadIdx.x & 63;
    if (n >= N) return;
    int beg = rp[n];
    int end = rp[n + 1];
    float acc = 0.0f;
    int j = beg;
    for (; j + 3 < end; j += 4) {
        int c0 = col[j + 0];
        int c1 = col[j + 1];
        int c2 = col[j + 2];
        int c3 = col[j + 3];
        float a0 = w[(size_t)c0 * DIM + lane];
        float a1 = w[(size_t)c1 * DIM + lane];
        float a2 = w[(size_t)c2 * DIM + lane];
        float a3 = w[(size_t)c3 * DIM + lane];
        acc += a0 + a1 + a2 + a3;
    }
    for (; j < end; ++j) {
        acc += w[(size_t)col[j] * DIM + lane];
    }
    float nm = norm[n];
    float v = acc * nm;                 // h_{k+1}[n, lane]
    float p = v * s[lane];
    #pragma unroll
    for (int off = 32; off; off >>= 1) p += __shfl_xor(p, off, 64);
    float gate = 1.0f / (1.0f + expf(-p));
    size_t idx = (size_t)n * DIM + lane;
    out[idx] += gate * v;
    if (write_next) wnext[idx] = v * nm;  // pre-scaled for next gather
}

extern "C" void kernel_launch(void* const* d_in, const int* in_sizes, int n_in,
                              void* d_out, int out_size, void* d_ws, size_t ws_size,
                              hipStream_t stream) {
    const float* feats = (const float*)d_in[0];
    const float* s     = (const float*)d_in[1];
    const int*   src   = (const int*)d_in[2];
    const int*   dst   = (const int*)d_in[3];
    float* out = (float*)d_out;

    const int N = in_sizes[0] / DIM;
    const int E = in_sizes[2];

    // workspace: [norm:N f][wA:N*64 f][wB:N*64 f][rp:N+1 i][deg:N i][cursor:N i][col:E i][chunk:256 i]
    float* norm   = (float*)d_ws;
    float* wA     = norm + N;
    float* wB     = wA + (size_t)N * DIM;
    int*   rp     = (int*)(wB + (size_t)N * DIM);
    int*   deg    = rp + (N + 1);
    int*   cursor = deg + N;
    int*   col    = cursor + N;
    int*   chunk  = col + E;

    const int BLK = 256;
    const int wavesPerBlk = BLK / 64;
    const int chunks = (N + 1023) / 1024;   // 98 for N=100000 (must be <= 256)

    zero_int_kernel<<<(N + BLK - 1) / BLK, BLK, 0, stream>>>(deg, N);
    degree_kernel<<<(E + BLK - 1) / BLK, BLK, 0, stream>>>(dst, deg, E);
    norm_kernel<<<(N + BLK - 1) / BLK, BLK, 0, stream>>>(deg, norm, N);

    // CSR build
    scan1_kernel<<<chunks, 256, 0, stream>>>(deg, rp, chunk, N);
    scan2_kernel<<<1, 256, 0, stream>>>(chunk, chunks);
    scan3_kernel<<<(N + BLK - 1) / BLK, BLK, 0, stream>>>(rp, chunk, cursor, N, E);
    fill_kernel<<<(E + BLK - 1) / BLK, BLK, 0, stream>>>(src, dst, cursor, col, E);

    // k = 0 readout + initial pre-scaled state
    int nodeBlocks = (N + wavesPerBlk - 1) / wavesPerBlk;
    init_kernel<<<nodeBlocks, BLK, 0, stream>>>(feats, norm, s, out, wA, N);

    const int K = 10;
    float* cur = wA;
    float* nxt = wB;
    for (int k = 0; k < K; ++k) {
        int write_next = (k < K - 1) ? 1 : 0;
        gather_hop_kernel<<<nodeBlocks, BLK, 0, stream>>>(cur, rp, col, norm, s,
                                                          out, nxt, N, write_next);
        float* t = cur; cur = nxt; nxt = t;
    }
}

// Round 4
// 851.093 us; speedup vs baseline: 3.5596x; 1.0663x over previous
//
#include <hip/hip_runtime.h>
#include <hip/hip_bf16.h>
#include <hip/hip_fp16.h>
#include <math.h>

// DAGNN propagation, CSR-gather formulation, fp16 propagation state:
//   deg[n]  = in-degree (incl. self loop), norm = deg^-0.5
//   w_0 = half(feats * norm)                (pre-scaled state, fp16)
//   per hop: acc[n] = sum_j float(w[col[j]])   (plain gather, fp32 accum)
//            v = acc * norm[n]              (= h_{k+1}[n], fp32)
//            out[n] += sigmoid(v . s) * v   (streamed readout, fp32)
//            w_next[n] = half(v * norm[n])  (pre-scale for next hop)

#define DIM 64

// ---- zero int region ----
__global__ void zero_int_kernel(int* __restrict__ p, int n) {
    int i = blockIdx.x * blockDim.x + threadIdx.x;
    if (i < n) p[i] = 0;
}

// ---- in-degree (int atomics) ----
__global__ void degree_kernel(const int* __restrict__ dst, int* __restrict__ deg, int E) {
    int e = blockIdx.x * blockDim.x + threadIdx.x;
    if (e < E) atomicAdd(&deg[dst[e]], 1);
}

// ---- norm = deg^-0.5 ----
__global__ void norm_kernel(const int* __restrict__ deg, float* __restrict__ norm, int N) {
    int i = blockIdx.x * blockDim.x + threadIdx.x;
    if (i < N) norm[i] = rsqrtf((float)deg[i]);
}

// ---- exclusive scan, stage 1: per-1024-chunk scan + chunk totals ----
__global__ void scan1_kernel(const int* __restrict__ deg, int* __restrict__ rp,
                             int* __restrict__ chunk_sums, int N) {
    __shared__ int lds[256];
    int t = threadIdx.x;
    int base = blockIdx.x * 1024 + t * 4;
    int v0 = (base + 0 < N) ? deg[base + 0] : 0;
    int v1 = (base + 1 < N) ? deg[base + 1] : 0;
    int v2 = (base + 2 < N) ? deg[base + 2] : 0;
    int v3 = (base + 3 < N) ? deg[base + 3] : 0;
    int tsum = v0 + v1 + v2 + v3;
    lds[t] = tsum;
    __syncthreads();
    for (int off = 1; off < 256; off <<= 1) {
        int x = (t >= off) ? lds[t - off] : 0;
        __syncthreads();
        lds[t] += x;
        __syncthreads();
    }
    int excl = lds[t] - tsum;
    if (t == 255) chunk_sums[blockIdx.x] = lds[255];
    int p = excl;
    if (base + 0 < N) rp[base + 0] = p; p += v0;
    if (base + 1 < N) rp[base + 1] = p; p += v1;
    if (base + 2 < N) rp[base + 2] = p; p += v2;
    if (base + 3 < N) rp[base + 3] = p;
}

// ---- exclusive scan, stage 2: scan chunk totals (single block, B <= 256) ----
__global__ void scan2_kernel(int* __restrict__ chunk_sums, int B) {
    __shared__ int lds[256];
    int t = threadIdx.x;
    int v = (t < B) ? chunk_sums[t] : 0;
    lds[t] = v;
    __syncthreads();
    for (int off = 1; off < 256; off <<= 1) {
        int x = (t >= off) ? lds[t - off] : 0;
        __syncthreads();
        lds[t] += x;
        __syncthreads();
    }
    if (t < B) chunk_sums[t] = lds[t] - v;  // exclusive
}

// ---- exclusive scan, stage 3: add chunk offsets; init cursor; rp[N]=E ----
__global__ void scan3_kernel(int* __restrict__ rp, const int* __restrict__ chunk_sums,
                             int* __restrict__ cursor, int N, int E) {
    int i = blockIdx.x * blockDim.x + threadIdx.x;
    if (i < N) {
        int val = rp[i] + chunk_sums[i >> 10];
        rp[i] = val;
        cursor[i] = val;
    }
    if (i == 0) rp[N] = E;
}

// ---- CSR fill: col[pos] = src[e], pos allocated per dst row ----
__global__ void fill_kernel(const int* __restrict__ src, const int* __restrict__ dst,
                            int* __restrict__ cursor, int* __restrict__ col, int E) {
    int e = blockIdx.x * blockDim.x + threadIdx.x;
    if (e < E) {
        int d = dst[e];
        int pos = atomicAdd(&cursor[d], 1);
        col[pos] = src[e];
    }
}

// ---- init: out = sigmoid(feats.s)*feats ; w0 = half(feats*norm) ----
__global__ void init_kernel(const float* __restrict__ feats,
                            const float* __restrict__ norm,
                            const float* __restrict__ s,
                            float* __restrict__ out,
                            __half* __restrict__ w, int N) {
    int n = blockIdx.x * (blockDim.x >> 6) + (threadIdx.x >> 6);
    int lane = threadIdx.x & 63;
    if (n >= N) return;
    size_t idx = (size_t)n * DIM + lane;
    float v = feats[idx];
    float p = v * s[lane];
    #pragma unroll
    for (int off = 32; off; off >>= 1) p += __shfl_xor(p, off, 64);
    float gate = 1.0f / (1.0f + expf(-p));
    out[idx] = gate * v;
    w[idx] = __float2half(v * norm[n]);
}

// ---- fused hop: CSR gather (fp16) + norm + gate + out-accum + next-state ----
__global__ void gather_hop_kernel(const __half* __restrict__ w,
                                  const int* __restrict__ rp,
                                  const int* __restrict__ col,
                                  const float* __restrict__ norm,
                                  const float* __restrict__ s,
                                  float* __restrict__ out,
                                  __half* __restrict__ wnext,
                                  int N, int write_next) {
    int n = blockIdx.x * (blockDim.x >> 6) + (threadIdx.x >> 6);
    int lane = threadIdx.x & 63;
    if (n >= N) return;
    int beg = rp[n];
    int end = rp[n + 1];
    float acc = 0.0f;
    int j = beg;
    for (; j + 3 < end; j += 4) {
        int c0 = col[j + 0];
        int c1 = col[j + 1];
        int c2 = col[j + 2];
        int c3 = col[j + 3];
        float a0 = __half2float(w[(size_t)c0 * DIM + lane]);
        float a1 = __half2float(w[(size_t)c1 * DIM + lane]);
        float a2 = __half2float(w[(size_t)c2 * DIM + lane]);
        float a3 = __half2float(w[(size_t)c3 * DIM + lane]);
        acc += a0 + a1 + a2 + a3;
    }
    for (; j < end; ++j) {
        acc += __half2float(w[(size_t)col[j] * DIM + lane]);
    }
    float nm = norm[n];
    float v = acc * nm;                 // h_{k+1}[n, lane]
    float p = v * s[lane];
    #pragma unroll
    for (int off = 32; off; off >>= 1) p += __shfl_xor(p, off, 64);
    float gate = 1.0f / (1.0f + expf(-p));
    size_t idx = (size_t)n * DIM + lane;
    out[idx] += gate * v;
    if (write_next) wnext[idx] = __float2half(v * nm);  // pre-scaled for next gather
}

extern "C" void kernel_launch(void* const* d_in, const int* in_sizes, int n_in,
                              void* d_out, int out_size, void* d_ws, size_t ws_size,
                              hipStream_t stream) {
    const float* feats = (const float*)d_in[0];
    const float* s     = (const float*)d_in[1];
    const int*   src   = (const int*)d_in[2];
    const int*   dst   = (const int*)d_in[3];
    float* out = (float*)d_out;

    const int N = in_sizes[0] / DIM;
    const int E = in_sizes[2];

    // workspace: [norm:N f][wA:N*64 h][wB:N*64 h][rp:N+1 i][deg:N i][cursor:N i][col:E i][chunk:256 i]
    float*  norm   = (float*)d_ws;
    __half* wA     = (__half*)(norm + N);
    __half* wB     = wA + (size_t)N * DIM;
    int*    rp     = (int*)(wB + (size_t)N * DIM);
    int*    deg    = rp + (N + 1);
    int*    cursor = deg + N;
    int*    col    = cursor + N;

    const int BLK = 256;
    const int wavesPerBlk = BLK / 64;
    const int chunks = (N + 1023) / 1024;   // 98 for N=100000 (must be <= 256)
    int* chunk = col + E;

    zero_int_kernel<<<(N + BLK - 1) / BLK, BLK, 0, stream>>>(deg, N);
    degree_kernel<<<(E + BLK - 1) / BLK, BLK, 0, stream>>>(dst, deg, E);
    norm_kernel<<<(N + BLK - 1) / BLK, BLK, 0, stream>>>(deg, norm, N);

    // CSR build
    scan1_kernel<<<chunks, 256, 0, stream>>>(deg, rp, chunk, N);
    scan2_kernel<<<1, 256, 0, stream>>>(chunk, chunks);
    scan3_kernel<<<(N + BLK - 1) / BLK, BLK, 0, stream>>>(rp, chunk, cursor, N, E);
    fill_kernel<<<(E + BLK - 1) / BLK, BLK, 0, stream>>>(src, dst, cursor, col, E);

    // k = 0 readout + initial pre-scaled state
    int nodeBlocks = (N + wavesPerBlk - 1) / wavesPerBlk;
    init_kernel<<<nodeBlocks, BLK, 0, stream>>>(feats, norm, s, out, wA, N);

    const int K = 10;
    __half* cur = wA;
    __half* nxt = wB;
    for (int k = 0; k < K; ++k) {
        int write_next = (k < K - 1) ? 1 : 0;
        gather_hop_kernel<<<nodeBlocks, BLK, 0, stream>>>(cur, rp, col, norm, s,
                                                          out, nxt, N, write_next);
        __half* t = cur; cur = nxt; nxt = t;
    }
}

// Round 5
// 704.216 us; speedup vs baseline: 4.3020x; 1.2086x over previous
//
#include <hip/hip_runtime.h>
#include <hip/hip_bf16.h>
#include <hip/hip_fp16.h>
#include <math.h>

// DAGNN propagation, CSR-gather formulation, fp16 state, wide gather:
//   lane = (edge_slot e in [0,8)) x (feature chunk c in [0,8))
//   each lane gathers 16B (8 fp16) -> 8 edges per wave-instruction.
//   w is pre-scaled by norm, so hop = gather-sum, *norm, gate, accumulate.

#define DIM 64

// ---- zero int region ----
__global__ void zero_int_kernel(int* __restrict__ p, int n) {
    int i = blockIdx.x * blockDim.x + threadIdx.x;
    if (i < n) p[i] = 0;
}

// ---- in-degree (int atomics) ----
__global__ void degree_kernel(const int* __restrict__ dst, int* __restrict__ deg, int E) {
    int e = blockIdx.x * blockDim.x + threadIdx.x;
    if (e < E) atomicAdd(&deg[dst[e]], 1);
}

// ---- norm = deg^-0.5 ----
__global__ void norm_kernel(const int* __restrict__ deg, float* __restrict__ norm, int N) {
    int i = blockIdx.x * blockDim.x + threadIdx.x;
    if (i < N) norm[i] = rsqrtf((float)deg[i]);
}

// ---- exclusive scan, stage 1: per-1024-chunk scan + chunk totals ----
__global__ void scan1_kernel(const int* __restrict__ deg, int* __restrict__ rp,
                             int* __restrict__ chunk_sums, int N) {
    __shared__ int lds[256];
    int t = threadIdx.x;
    int base = blockIdx.x * 1024 + t * 4;
    int v0 = (base + 0 < N) ? deg[base + 0] : 0;
    int v1 = (base + 1 < N) ? deg[base + 1] : 0;
    int v2 = (base + 2 < N) ? deg[base + 2] : 0;
    int v3 = (base + 3 < N) ? deg[base + 3] : 0;
    int tsum = v0 + v1 + v2 + v3;
    lds[t] = tsum;
    __syncthreads();
    for (int off = 1; off < 256; off <<= 1) {
        int x = (t >= off) ? lds[t - off] : 0;
        __syncthreads();
        lds[t] += x;
        __syncthreads();
    }
    int excl = lds[t] - tsum;
    if (t == 255) chunk_sums[blockIdx.x] = lds[255];
    int p = excl;
    if (base + 0 < N) rp[base + 0] = p; p += v0;
    if (base + 1 < N) rp[base + 1] = p; p += v1;
    if (base + 2 < N) rp[base + 2] = p; p += v2;
    if (base + 3 < N) rp[base + 3] = p;
}

// ---- exclusive scan, stage 2: scan chunk totals (single block, B <= 256) ----
__global__ void scan2_kernel(int* __restrict__ chunk_sums, int B) {
    __shared__ int lds[256];
    int t = threadIdx.x;
    int v = (t < B) ? chunk_sums[t] : 0;
    lds[t] = v;
    __syncthreads();
    for (int off = 1; off < 256; off <<= 1) {
        int x = (t >= off) ? lds[t - off] : 0;
        __syncthreads();
        lds[t] += x;
        __syncthreads();
    }
    if (t < B) chunk_sums[t] = lds[t] - v;  // exclusive
}

// ---- exclusive scan, stage 3: add chunk offsets; init cursor; rp[N]=E ----
__global__ void scan3_kernel(int* __restrict__ rp, const int* __restrict__ chunk_sums,
                             int* __restrict__ cursor, int N, int E) {
    int i = blockIdx.x * blockDim.x + threadIdx.x;
    if (i < N) {
        int val = rp[i] + chunk_sums[i >> 10];
        rp[i] = val;
        cursor[i] = val;
    }
    if (i == 0) rp[N] = E;
}

// ---- CSR fill: col[pos] = src[e], pos allocated per dst row ----
__global__ void fill_kernel(const int* __restrict__ src, const int* __restrict__ dst,
                            int* __restrict__ cursor, int* __restrict__ col, int E) {
    int e = blockIdx.x * blockDim.x + threadIdx.x;
    if (e < E) {
        int d = dst[e];
        int pos = atomicAdd(&cursor[d], 1);
        col[pos] = src[e];
    }
}

// ---- init: out = sigmoid(feats.s)*feats ; w0 = half(feats*norm) ----
__global__ void init_kernel(const float* __restrict__ feats,
                            const float* __restrict__ norm,
                            const float* __restrict__ s,
                            float* __restrict__ out,
                            __half* __restrict__ w, int N) {
    int n = blockIdx.x * (blockDim.x >> 6) + (threadIdx.x >> 6);
    int lane = threadIdx.x & 63;
    if (n >= N) return;
    size_t idx = ((size_t)n << 6) + lane;
    float v = feats[idx];
    float p = v * s[lane];
    #pragma unroll
    for (int off = 32; off; off >>= 1) p += __shfl_xor(p, off, 64);
    float gate = 1.0f / (1.0f + expf(-p));
    out[idx] = gate * v;
    w[idx] = __float2half(v * norm[n]);
}

// ---- fused hop: wide CSR gather (8 edges / wave-instruction) ----
__global__ void gather_hop_kernel(const __half* __restrict__ w,
                                  const int* __restrict__ rp,
                                  const int* __restrict__ col,
                                  const float* __restrict__ norm,
                                  const float* __restrict__ s,
                                  float* __restrict__ out,
                                  __half* __restrict__ wnext,
                                  int N, int write_next) {
    int n = blockIdx.x * (blockDim.x >> 6) + (threadIdx.x >> 6);
    if (n >= N) return;
    int lane = threadIdx.x & 63;
    int e_sub = lane >> 3;   // edge slot 0..7
    int c     = lane & 7;    // feature chunk 0..7 (8 fp16 = 16B)

    int beg = rp[n];
    int end = rp[n + 1];

    float acc[8];
    #pragma unroll
    for (int i = 0; i < 8; ++i) acc[i] = 0.0f;

    for (int j = beg + e_sub; j < end; j += 8) {
        int cc = col[j];
        float4 raw = *(const float4*)(w + ((size_t)cc << 6) + (c << 3));
        const __half2* h2 = (const __half2*)&raw;
        float2 f0 = __half22float2(h2[0]);
        float2 f1 = __half22float2(h2[1]);
        float2 f2 = __half22float2(h2[2]);
        float2 f3 = __half22float2(h2[3]);
        acc[0] += f0.x; acc[1] += f0.y;
        acc[2] += f1.x; acc[3] += f1.y;
        acc[4] += f2.x; acc[5] += f2.y;
        acc[6] += f3.x; acc[7] += f3.y;
    }

    // fold edge slots: lanes differing in bits 3..5
    #pragma unroll
    for (int off = 8; off < 64; off <<= 1) {
        #pragma unroll
        for (int i = 0; i < 8; ++i) acc[i] += __shfl_xor(acc[i], off, 64);
    }

    float nm = norm[n];
    float v[8];
    #pragma unroll
    for (int i = 0; i < 8; ++i) v[i] = acc[i] * nm;   // h_{k+1}[n, 8c..8c+7]

    // gate: dot(v, s) — partial over own chunk, reduce over c (bits 0..2)
    float4 sa = *(const float4*)(s + (c << 3));
    float4 sb = *(const float4*)(s + (c << 3) + 4);
    float p = v[0] * sa.x + v[1] * sa.y + v[2] * sa.z + v[3] * sa.w
            + v[4] * sb.x + v[5] * sb.y + v[6] * sb.z + v[7] * sb.w;
    #pragma unroll
    for (int off = 1; off < 8; off <<= 1) p += __shfl_xor(p, off, 64);
    float gate = 1.0f / (1.0f + expf(-p));

    size_t base = ((size_t)n << 6) + (c << 3);
    if (e_sub == 0) {
        // out RMW: 8 contiguous fp32 per lane, lanes c=0..7 cover the row
        float4* o = (float4*)(out + base);
        float4 o0 = o[0], o1 = o[1];
        o0.x += gate * v[0]; o0.y += gate * v[1];
        o0.z += gate * v[2]; o0.w += gate * v[3];
        o1.x += gate * v[4]; o1.y += gate * v[5];
        o1.z += gate * v[6]; o1.w += gate * v[7];
        o[0] = o0; o[1] = o1;
    } else if (e_sub == 1 && write_next) {
        // wnext = half(v*nm): 8 fp16 = 16B per lane
        __half2 hv[4];
        hv[0] = __floats2half2_rn(v[0] * nm, v[1] * nm);
        hv[1] = __floats2half2_rn(v[2] * nm, v[3] * nm);
        hv[2] = __floats2half2_rn(v[4] * nm, v[5] * nm);
        hv[3] = __floats2half2_rn(v[6] * nm, v[7] * nm);
        *(float4*)(wnext + base) = *(const float4*)hv;
    }
}

extern "C" void kernel_launch(void* const* d_in, const int* in_sizes, int n_in,
                              void* d_out, int out_size, void* d_ws, size_t ws_size,
                              hipStream_t stream) {
    const float* feats = (const float*)d_in[0];
    const float* s     = (const float*)d_in[1];
    const int*   src   = (const int*)d_in[2];
    const int*   dst   = (const int*)d_in[3];
    float* out = (float*)d_out;

    const int N = in_sizes[0] / DIM;
    const int E = in_sizes[2];

    // workspace: [norm:N f][wA:N*64 h][wB:N*64 h][rp:N+1 i][deg:N i][cursor:N i][col:E i][chunk:256 i]
    float*  norm   = (float*)d_ws;
    __half* wA     = (__half*)(norm + N);
    __half* wB     = wA + (size_t)N * DIM;
    int*    rp     = (int*)(wB + (size_t)N * DIM);
    int*    deg    = rp + (N + 1);
    int*    cursor = deg + N;
    int*    col    = cursor + N;
    int*    chunk  = col + E;

    const int BLK = 256;
    const int wavesPerBlk = BLK / 64;
    const int chunks = (N + 1023) / 1024;   // 98 for N=100000 (must be <= 256)

    zero_int_kernel<<<(N + BLK - 1) / BLK, BLK, 0, stream>>>(deg, N);
    degree_kernel<<<(E + BLK - 1) / BLK, BLK, 0, stream>>>(dst, deg, E);
    norm_kernel<<<(N + BLK - 1) / BLK, BLK, 0, stream>>>(deg, norm, N);

    // CSR build
    scan1_kernel<<<chunks, 256, 0, stream>>>(deg, rp, chunk, N);
    scan2_kernel<<<1, 256, 0, stream>>>(chunk, chunks);
    scan3_kernel<<<(N + BLK - 1) / BLK, BLK, 0, stream>>>(rp, chunk, cursor, N, E);
    fill_kernel<<<(E + BLK - 1) / BLK, BLK, 0, stream>>>(src, dst, cursor, col, E);

    // k = 0 readout + initial pre-scaled state
    int nodeBlocks = (N + wavesPerBlk - 1) / wavesPerBlk;
    init_kernel<<<nodeBlocks, BLK, 0, stream>>>(feats, norm, s, out, wA, N);

    const int K = 10;
    __half* cur = wA;
    __half* nxt = wB;
    for (int k = 0; k < K; ++k) {
        int write_next = (k < K - 1) ? 1 : 0;
        gather_hop_kernel<<<nodeBlocks, BLK, 0, stream>>>(cur, rp, col, norm, s,
                                                          out, nxt, N, write_next);
        __half* t = cur; cur = nxt; nxt = t;
    }
}